// Round 1
// 522.756 us; speedup vs baseline: 1.1383x; 1.1383x over previous
//
#include <hip/hip_runtime.h>
#include <stdint.h>

#define IN_DIM 8192
#define OUT_DIM 4096
#define NNZ 1638400
#define BATCH 4096

typedef __bf16 bf16x8 __attribute__((ext_vector_type(8)));
typedef float f32x4 __attribute__((ext_vector_type(4)));
typedef short s16x2 __attribute__((ext_vector_type(2)));

// ---- helpers ----------------------------------------------------------------

__device__ __forceinline__ unsigned short f2bf(float f) {
  union { float f; unsigned int u; } v; v.f = f;
  unsigned int u = v.u;
  unsigned int r = (u + 0x7FFFu + ((u >> 16) & 1u)) >> 16;  // RNE
  return (unsigned short)r;
}

__device__ __forceinline__ float bf2f(unsigned short b) {
  union { unsigned int u; float f; } v;
  v.u = (unsigned int)b << 16;
  return v.f;
}

__device__ __forceinline__ void async16(const void* g, void* l) {
  __builtin_amdgcn_global_load_lds(
      (const __attribute__((address_space(1))) unsigned int*)g,
      (__attribute__((address_space(3))) unsigned int*)l,
      16, 0, 0);
}

__device__ __forceinline__ void convert_body(int i, const float* __restrict__ src,
                                             unsigned short* __restrict__ dst) {
  const float4* s = (const float4*)src;
  float4 a = s[2 * i];
  float4 b = s[2 * i + 1];
  union { unsigned short us[8]; uint4 v; } o;
  o.us[0] = f2bf(a.x); o.us[1] = f2bf(a.y); o.us[2] = f2bf(a.z); o.us[3] = f2bf(a.w);
  o.us[4] = f2bf(b.x); o.us[5] = f2bf(b.y); o.us[6] = f2bf(b.z); o.us[7] = f2bf(b.w);
  ((uint4*)dst)[i] = o.v;
}

// ---- kernel 1: zero W_bf16 + convert x (unchanged, ~BW roofline) ------------

#define PREP_BLOCKS ((IN_DIM * OUT_DIM) / 8 / 256)  // 16384

__global__ void prep_kernel(uint4* __restrict__ W_zero,
                            const float* __restrict__ x,
                            unsigned short* __restrict__ x_bf16) {
  int i = blockIdx.x * 256 + threadIdx.x;
  W_zero[i] = make_uint4(0, 0, 0, 0);
  convert_body(i, x, x_bf16);
}

// ---- kernel 2: scatter-add into bf16 W --------------------------------------
// Preferred: hardware global_atomic_pk_add_bf16 (1 fire-and-forget op/nnz,
// no read-modify-write loop). Fallback: CAS, but seeded with a zero-word
// guess (most target words are untouched) to skip the initial load.

#if defined(__has_builtin)
#  if __has_builtin(__builtin_amdgcn_global_atomic_fadd_v2bf16)
#    define HAVE_PK_BF16 1
#  endif
#endif

__device__ __forceinline__ void scat1(int c, int r, float w,
                                      unsigned int* __restrict__ W) {
  size_t e = (size_t)c * IN_DIM + r;     // element index in W^T [OUT][IN]
  const bool hi = (e & 1);
  unsigned short nb = f2bf(w);
#ifdef HAVE_PK_BF16
  s16x2 v;
  v.x = hi ? (short)0 : (short)nb;
  v.y = hi ? (short)nb : (short)0;
  __builtin_amdgcn_global_atomic_fadd_v2bf16(
      (__attribute__((address_space(1))) s16x2*)(W + (e >> 1)), v);
#else
  unsigned int* p = W + (e >> 1);
  unsigned int nw0 = hi ? ((unsigned int)nb << 16) : (unsigned int)nb;
  unsigned int cur = atomicCAS(p, 0u, nw0);   // fast path: word still zero
  if (cur == 0u) return;
  unsigned int assumed;
  do {
    assumed = cur;
    unsigned short h = hi ? (unsigned short)(assumed >> 16)
                          : (unsigned short)(assumed & 0xFFFFu);
    unsigned short b2 = f2bf(bf2f(h) + w);
    unsigned int nw = hi ? ((assumed & 0x0000FFFFu) | ((unsigned int)b2 << 16))
                         : ((assumed & 0xFFFF0000u) | (unsigned int)b2);
    cur = atomicCAS(p, assumed, nw);
  } while (cur != assumed);
#endif
}

#define SCAT_BLOCKS (NNZ / 4 / 256)  // 1600

__global__ void scatter_kernel(const int4* __restrict__ ri4,
                               const int4* __restrict__ ci4,
                               const float4* __restrict__ w4,
                               unsigned int* __restrict__ W) {
  int i = blockIdx.x * 256 + threadIdx.x;
  int4 r = ri4[i];
  int4 c = ci4[i];
  float4 w = w4[i];
  scat1(c.x, r.x, w.x, W);
  scat1(c.y, r.y, w.y, W);
  scat1(c.z, r.z, w.z, W);
  scat1(c.w, r.w, w.w, W);
}

// ---- kernel 3: bf16 GEMM, 256x256 tile, 8 waves, phase-interleaved ----------
// C[M,N] = A[M,K] * Bt[N,K]^T + bias.
// 512 thr (2M x 4N waves), per-wave 128x64 out = acc[8][4] 16x16x32 frags.
// LDS 128 KiB: 2 double-buffered K-tiles of (A 256x64 + B 256x64) bf16,
// XOR-swizzled 16B segments (verified conflict-free scheme carried over).
// Per K-tile: 4 phases {ds_read A-quad (+B all at q0) | stage 2 loads of
// kt+1 into dead buffer | s_barrier | setprio(1) 16 MFMA setprio(0) |
// s_barrier}. ONE counted s_waitcnt vmcnt(2) per K-tile (raw s_barrier so
// the compiler cannot insert a vmcnt(0) drain). XCD-swizzled 1-D grid.

#define TBM 256
#define TBN 256
#define TBK 64
#define NKT (IN_DIM / TBK)  // 128

__global__ __launch_bounds__(512, 2) void gemm_kernel(
    const unsigned short* __restrict__ A,   // [BATCH][IN_DIM] bf16 bits
    const unsigned short* __restrict__ Bt,  // [OUT_DIM][IN_DIM] bf16 bits
    const float* __restrict__ bias,         // [OUT_DIM]
    float* __restrict__ C) {                // [BATCH][OUT_DIM] fp32
  extern __shared__ __align__(16) unsigned short lds[];  // 131072 B

  const int tid = threadIdx.x;

  // bijective XCD swizzle: 256 workgroups, 8 XCDs, 32 each.
  const int bid = blockIdx.x;
  const int swz = ((bid & 7) << 5) | (bid >> 3);
  const int m0 = (swz & 15) * TBM;   // m fastest within XCD -> B-panel reuse in L2
  const int n0 = (swz >> 4) * TBN;

  const int wid = tid >> 6;
  const int lane = tid & 63;
  const int wm = wid >> 2;       // 0..1
  const int wn = wid & 3;        // 0..3
  const int quad = lane >> 4;
  const int lm = lane & 15;
  const int xorv = lm & 7;

  const unsigned short* Ab = A + (size_t)m0 * IN_DIM;
  const unsigned short* Bb = Bt + (size_t)n0 * IN_DIM;

  // staging geometry: tile = 256 rows x 8 segs of 16B; 512 thr -> 4 rounds.
  int soff[4], ldst[4];
#pragma unroll
  for (int c = 0; c < 4; ++c) {
    const int t2 = c * 512 + tid;
    const int srow = t2 >> 3;
    const int sseg = (t2 & 7) ^ (srow & 7);   // stage-side swizzle
    soff[c] = srow * IN_DIM + sseg * 8;
    ldst[c] = t2 * 16;                         // LDS byte offset (linear dest)
  }

  f32x4 acc[8][4] = {};

#define STAGE(kt_, b_, c_)                                                  \
  do {                                                                      \
    const int k0_ = (kt_)*TBK;                                              \
    char* la_ = (char*)lds + (b_)*65536;                                    \
    async16(Ab + (size_t)soff[c_] + k0_, la_ + ldst[c_]);                   \
    async16(Bb + (size_t)soff[c_] + k0_, la_ + 32768 + ldst[c_]);           \
  } while (0)

  // prologue: stage K-tile 0 fully into buf 0 (8 loads/thread)
#pragma unroll
  for (int c = 0; c < 4; ++c) STAGE(0, 0, c);

  for (int kt = 0; kt < NKT; ++kt) {
    const int buf = kt & 1;
    const int nbuf = buf ^ 1;
    const int ktn = (kt + 1) & (NKT - 1);  // wraps at the end: harmless dummy

    // issue next-tile group 0, then counted drain of THIS tile's 8 loads.
    STAGE(ktn, nbuf, 0);
    asm volatile("s_waitcnt vmcnt(2)" ::: "memory");
    __builtin_amdgcn_sched_barrier(0);
    __builtin_amdgcn_s_barrier();          // all waves: buf[buf] complete

    const unsigned short* lA = lds + buf * 32768;  // elements (64 KiB/buf)
    const unsigned short* lB = lA + 16384;

    // B fragments for the whole K-tile (8 x ds_read_b128, held in regs)
    bf16x8 bfr[4][2];
#pragma unroll
    for (int j = 0; j < 4; ++j) {
      const int row = wn * 64 + j * 16 + lm;
#pragma unroll
      for (int ss = 0; ss < 2; ++ss) {
        const int p = ((ss << 2) | quad) ^ xorv;   // read-side inverse swizzle
        bfr[j][ss] = *(const bf16x8*)(lB + row * TBK + p * 8);
      }
    }

#pragma unroll
    for (int q = 0; q < 4; ++q) {
      bf16x8 af[2][2];
#pragma unroll
      for (int i = 0; i < 2; ++i) {
        const int row = wm * 128 + (q * 2 + i) * 16 + lm;
#pragma unroll
        for (int ss = 0; ss < 2; ++ss) {
          const int p = ((ss << 2) | quad) ^ xorv;
          af[i][ss] = *(const bf16x8*)(lA + row * TBK + p * 8);
        }
      }
      if (q < 3) STAGE(ktn, nbuf, q + 1);  // dead buffer: no WAR hazard
      __builtin_amdgcn_s_barrier();
      __builtin_amdgcn_s_setprio(1);
#pragma unroll
      for (int i = 0; i < 2; ++i)
#pragma unroll
        for (int j = 0; j < 4; ++j)
#pragma unroll
          for (int ss = 0; ss < 2; ++ss)
            acc[q * 2 + i][j] = __builtin_amdgcn_mfma_f32_16x16x32_bf16(
                af[i][ss], bfr[j][ss], acc[q * 2 + i][j], 0, 0, 0);
      __builtin_amdgcn_s_setprio(0);
      __builtin_amdgcn_s_barrier();
    }
  }
#undef STAGE

  // Epilogue: C/D layout col = lane&15, row = quad*4 + reg  [m89-verified]
  const int ccol0 = n0 + wn * 64 + lm;
  const int crow0 = m0 + wm * 128;
#pragma unroll
  for (int j = 0; j < 4; ++j) {
    const int col = ccol0 + j * 16;
    const float bv = bias[col];
#pragma unroll
    for (int i = 0; i < 8; ++i) {
#pragma unroll
      for (int v = 0; v < 4; ++v) {
        const int row = crow0 + i * 16 + quad * 4 + v;
        C[(size_t)row * OUT_DIM + col] = acc[i][j][v] + bv;
      }
    }
  }
}

// ---- launch -----------------------------------------------------------------

extern "C" void kernel_launch(void* const* d_in, const int* in_sizes, int n_in,
                              void* d_out, int out_size, void* d_ws, size_t ws_size,
                              hipStream_t stream) {
  const float* x = (const float*)d_in[0];       // [4096][8192] fp32
  const int* row_idx = (const int*)d_in[1];     // [NNZ] int32
  const int* col_idx = (const int*)d_in[2];     // [NNZ] int32
  const float* weights = (const float*)d_in[3]; // [NNZ] fp32
  const float* bias = (const float*)d_in[4];    // [4096] fp32
  float* out = (float*)d_out;                   // [4096][4096] fp32

  // ws layout: W_bf16 [0,64M), x_bf16 [64M,128M).
  const size_t W_BF16_BYTES = (size_t)IN_DIM * OUT_DIM * 2;  // 64 MiB
  unsigned short* W_bf16 = (unsigned short*)d_ws;
  unsigned short* x_bf16 = (unsigned short*)((char*)d_ws + W_BF16_BYTES);

  static bool attr_set = false;
  if (!attr_set) {
    (void)hipFuncSetAttribute((const void*)gemm_kernel,
                              hipFuncAttributeMaxDynamicSharedMemorySize,
                              131072);
    attr_set = true;
  }

  // 1. zero W_bf16 + convert x -> bf16
  prep_kernel<<<PREP_BLOCKS, 256, 0, stream>>>((uint4*)W_bf16, x, x_bf16);

  // 2. scatter-add weights into bf16 W^T
  scatter_kernel<<<SCAT_BLOCKS, 256, 0, stream>>>(
      (const int4*)row_idx, (const int4*)col_idx, (const float4*)weights,
      (unsigned int*)W_bf16);

  // 3. GEMM + bias (256^2 tile, 8 waves, XCD-swizzled 1-D grid of 256)
  gemm_kernel<<<dim3(256), dim3(512), 131072, stream>>>(x_bf16, W_bf16, bias, out);
}